// Round 13
// baseline (51.869 us; speedup 1.0000x reference)
//
#include <hip/hip_runtime.h>
#include <hip/hip_bf16.h>

#define M_DIM 4096
#define N_DIM 4096
#define K_DIM 1024
#define NT (K_DIM / 64)   // 16 K-tiles of BK=64

typedef short short8 __attribute__((ext_vector_type(8)));
typedef unsigned short ushort8 __attribute__((ext_vector_type(8)));
typedef unsigned short ushort4v __attribute__((ext_vector_type(4)));
typedef float f32x4 __attribute__((ext_vector_type(4)));
typedef float f32x16 __attribute__((ext_vector_type(16)));

// fp32 -> bf16 round-to-nearest-even (bias-free over the K-sum)
__device__ __forceinline__ unsigned short f2bf_rne(float f) {
    union { float f; unsigned u; } v;
    v.f = f;
    unsigned u = v.u;
    u += 0x7FFFu + ((u >> 16) & 1u);
    return (unsigned short)(u >> 16);
}

// async global->LDS, 16B/lane. LDS dest = wave-uniform base + lane*16.
__device__ __forceinline__ void gload16(const void* g, void* l) {
    __builtin_amdgcn_global_load_lds(
        (const __attribute__((address_space(1))) void*)g,
        (__attribute__((address_space(3))) void*)l,
        16, 0, 0);
}

// ---- merged conversion (R7-verified, at HBM roofline ~7.6us) ----
__global__ __launch_bounds__(256) void cvt_kernel(const float* __restrict__ A,
                                                  const float* __restrict__ B,
                                                  unsigned short* __restrict__ Aw,
                                                  unsigned short* __restrict__ Bw) {
    __shared__ unsigned short tile[64][68];   // +4 pad
    if (blockIdx.x < 2048) {
        size_t i = (size_t)blockIdx.x * 256 + threadIdx.x;
        const f32x4* s = (const f32x4*)A + i * 2;
        f32x4 v0 = s[0], v1 = s[1];
        ushort8 o;
        o[0] = f2bf_rne(v0[0]); o[1] = f2bf_rne(v0[1]);
        o[2] = f2bf_rne(v0[2]); o[3] = f2bf_rne(v0[3]);
        o[4] = f2bf_rne(v1[0]); o[5] = f2bf_rne(v1[1]);
        o[6] = f2bf_rne(v1[2]); o[7] = f2bf_rne(v1[3]);
        *(ushort8*)(Aw + i * 8) = o;
    } else {
        int bb = blockIdx.x - 2048;               // 0..1023
        int bn = bb & 63, bk = bb >> 6;           // 64 n-tiles x 16 k-tiles
        int n0 = bn * 64, k0 = bk * 64;
        int kr = threadIdx.x >> 4;                // 0..15
        int nc = threadIdx.x & 15;
#pragma unroll
        for (int p = 0; p < 4; ++p) {
            int k = kr + p * 16;
            f32x4 v = *(const f32x4*)&B[(size_t)(k0 + k) * N_DIM + n0 + nc * 4];
            ushort4v u;
            u[0] = f2bf_rne(v[0]); u[1] = f2bf_rne(v[1]);
            u[2] = f2bf_rne(v[2]); u[3] = f2bf_rne(v[3]);
            *(ushort4v*)&tile[k][nc * 4] = u;
        }
        __syncthreads();
#pragma unroll
        for (int p = 0; p < 4; ++p) {
            int n = kr + p * 16;
            ushort4v o;
#pragma unroll
            for (int j = 0; j < 4; ++j) o[j] = tile[nc * 4 + j][n];
            *(ushort4v*)&Bw[(size_t)(n0 + n) * K_DIM + k0 + nc * 4] = o;
        }
    }
}

// ---- 256x256x64 GEMM, R7 schedule ported to mfma_f32_32x32x16_bf16 ----
// 8 waves (2Mx4N), per-wave 128x64 = acc[4][2] f32x16 (4m x 2n frags of 32x32).
// K-tile 64 = 4 k16-steps. Subphase q: 4 MFMA (2m x 2n, one k-step) using regs
// read in q-1; issue 2 A-reads + 1 B-read for q+1. bvE = k-steps 0,1 / bvL = 2,3.
// Sync identical to R7: 3 barriers (q3 +vmcnt(2), q4, q7 +vmcnt(6)) per tile.
__global__ __launch_bounds__(512, 1) void gemm8_kernel(const unsigned short* __restrict__ A,
                                                       const unsigned short* __restrict__ Bt,
                                                       float* __restrict__ C) {
    __shared__ __align__(16) unsigned short lds[2][2][256 * 64];  // [buf][0=A,1=B]

    int bid = blockIdx.x;
    int xcd = bid & 7, ii = bid >> 3;
    int tm = xcd * 2 + (ii & 1);
    int tn = ii >> 1;
    int bM = tm * 256, bN = tn * 256;

    int tid = threadIdx.x;
    int wid = tid >> 6, lane = tid & 63;
    int wm = wid >> 2, wn = wid & 3;

    int srow = lane >> 3;
    int cslot = (lane & 7) ^ srow;
    int stg_row = wid * 8 + srow;

    const unsigned short* gA = A + (size_t)(bM + stg_row) * K_DIM + cslot * 8;
    const unsigned short* gB = Bt + (size_t)(bN + stg_row) * K_DIM + cslot * 8;

#define STG(mat, unit, buf, kt)                                                        \
    gload16((mat ? gB : gA) + (size_t)((unit) * 64) * K_DIM + (size_t)(kt) * 64,       \
            (char*)&lds[(buf)][(mat)][0] + (unit) * 8192 + wid * 1024)

    // 32x32 fragment addressing: row = base + m*32 + (lane&31); 16B slot for
    // k-step s = (s*2 + (lane>>5)) ^ (lane&7)   [row&7 == lane&7]
    int rA = wm * 128 + (lane & 31);
    int rB = wn * 64 + (lane & 31);
    int l5 = lane >> 5;
    int l7 = lane & 7;

#define LDA(buf, m, s) \
    (*(const short8*)&lds[(buf)][0][(rA + (m) * 32) * 64 + ((((s) * 2 + l5) ^ l7) * 8)])
#define LDB(buf, n, s) \
    (*(const short8*)&lds[(buf)][1][(rB + (n) * 32) * 64 + ((((s) * 2 + l5) ^ l7) * 8)])

    f32x16 acc[4][2];
#pragma unroll
    for (int m = 0; m < 4; ++m)
#pragma unroll
        for (int n = 0; n < 2; ++n)
            acc[m][n] = (f32x16)(0.f);

    short8 avP[2], avQ[2];       // m-pair ping-pong (one k-step)
    short8 bvE[2][2], bvL[2][2]; // [k-step 0|1][n] and [k-step 2|3][n]

#define SB0 __builtin_amdgcn_sched_barrier(0);
#define BAR                                    \
    __builtin_amdgcn_sched_barrier(0);         \
    __builtin_amdgcn_s_barrier();              \
    __builtin_amdgcn_sched_barrier(0);

#define RD_AV(AV, BUF, MB, SS)                 \
    AV[0] = LDA(BUF, (MB), SS);                \
    AV[1] = LDA(BUF, (MB) + 1, SS);

#define MFMAQ(AV, BVS, MB)                                                             \
    __builtin_amdgcn_s_setprio(1);                                                     \
    _Pragma("unroll") for (int m2 = 0; m2 < 2; ++m2)                                   \
        _Pragma("unroll") for (int n = 0; n < 2; ++n)                                  \
            acc[(MB) + m2][n] = __builtin_amdgcn_mfma_f32_32x32x16_bf16(               \
                AV[m2], BVS[n], acc[(MB) + m2][n], 0, 0, 0);                           \
    __builtin_amdgcn_s_setprio(0);

    // steady tile: HT2 = (t+2 < NT) compile-path, VME = boundary vmcnt string
#define TILE(t, CB, NB, HT2, VME)                                                      \
    {                                                                                  \
        /* q0: MFMA m01@s0 */                                                          \
        RD_AV(avQ, CB, 2, 0) bvL[0][0] = LDB(CB, 0, 2);                                \
        STG(0, 1, NB, (t) + 1);                                                        \
        MFMAQ(avP, bvE[0], 0) SB0                                                      \
        /* q1: MFMA m23@s0 */                                                          \
        RD_AV(avP, CB, 0, 1) bvL[0][1] = LDB(CB, 1, 2);                                \
        STG(0, 3, NB, (t) + 1);                                                        \
        MFMAQ(avQ, bvE[0], 2) SB0                                                      \
        /* q2: MFMA m01@s1 */                                                          \
        RD_AV(avQ, CB, 2, 1) bvL[1][0] = LDB(CB, 0, 3);                                \
        MFMAQ(avP, bvE[1], 0) SB0                                                      \
        /* q3: MFMA m23@s1 */                                                          \
        RD_AV(avP, CB, 0, 2) bvL[1][1] = LDB(CB, 1, 3);                                \
        MFMAQ(avQ, bvE[1], 2)                                                          \
        asm volatile("s_waitcnt vmcnt(2)" ::: "memory");                               \
        BAR                                                                            \
        /* q4: MFMA m01@s2 */                                                          \
        RD_AV(avQ, CB, 2, 2) bvE[0][0] = LDB(NB, 0, 0);                                \
        if (HT2) { STG(1, 0, CB, (t) + 2); }                                           \
        MFMAQ(avP, bvL[0], 0)                                                          \
        BAR                                                                            \
        /* q5: MFMA m23@s2 */                                                          \
        RD_AV(avP, CB, 0, 3) bvE[0][1] = LDB(NB, 1, 0);                                \
        if (HT2) { STG(1, 1, CB, (t) + 2); STG(0, 0, CB, (t) + 2); }                   \
        MFMAQ(avQ, bvL[0], 2) SB0                                                      \
        /* q6: MFMA m01@s3 */                                                          \
        RD_AV(avQ, CB, 2, 3) bvE[1][0] = LDB(NB, 0, 1);                                \
        if (HT2) { STG(1, 2, CB, (t) + 2); STG(0, 2, CB, (t) + 2); }                   \
        MFMAQ(avP, bvL[1], 0) SB0                                                      \
        /* q7: MFMA m23@s3 */                                                          \
        RD_AV(avP, NB, 0, 0) bvE[1][1] = LDB(NB, 1, 1);                                \
        if (HT2) { STG(1, 3, CB, (t) + 2); }                                           \
        MFMAQ(avQ, bvL[1], 2)                                                          \
        asm volatile("s_waitcnt " VME ::: "memory");                                   \
        BAR                                                                            \
    }

    // ---- prologue: t0 all 8 units + t1's 6 (steady q4-7 order) ----
    STG(1, 0, 0, 0); STG(1, 1, 0, 0); STG(1, 2, 0, 0); STG(1, 3, 0, 0);
    STG(0, 0, 0, 0); STG(0, 1, 0, 0); STG(0, 2, 0, 0); STG(0, 3, 0, 0);
    STG(1, 0, 1, 1); STG(1, 1, 1, 1); STG(0, 0, 1, 1);
    STG(1, 2, 1, 1); STG(0, 2, 1, 1); STG(1, 3, 1, 1);
    asm volatile("s_waitcnt vmcnt(6)" ::: "memory");
    BAR
    // pre-reads for tile0 q0
    bvE[0][0] = LDB(0, 0, 0); bvE[0][1] = LDB(0, 1, 0);
    bvE[1][0] = LDB(0, 0, 1); bvE[1][1] = LDB(0, 1, 1);
    RD_AV(avP, 0, 0, 0)
    SB0

    for (int t = 0; t < NT - 2; t += 2) {
        TILE(t, 0, 1, true, "vmcnt(6)")
        TILE(t + 1, 1, 0, true, "vmcnt(6)")
    }
    TILE(NT - 2, 0, 1, false, "vmcnt(0)")

    // ---- last tile (buf 1): m-major order, barrier-free, fused C stores ----
    // C/D layout (m74/m101): col = lane&31, row = (r&3) + 8*(r>>2) + 4*(lane>>5)
    {
        size_t crow = (size_t)bM + wm * 128 + l5 * 4;
        int ccol = bN + wn * 64 + (lane & 31);
#define ST32(M)                                                                        \
        _Pragma("unroll") for (int n = 0; n < 2; ++n)                                  \
            _Pragma("unroll") for (int r = 0; r < 16; ++r)                             \
                C[(crow + (M) * 32 + (r & 3) + 8 * (r >> 2)) * N_DIM +                 \
                  ccol + n * 32] = acc[(M)][n][r];
        /* L0 */ RD_AV(avQ, 1, 0, 1) bvL[0][0] = LDB(1, 0, 2); MFMAQ(avP, bvE[0], 0) SB0
        /* L1 */ RD_AV(avP, 1, 0, 2) bvL[0][1] = LDB(1, 1, 2); MFMAQ(avQ, bvE[1], 0) SB0
        /* L2 */ RD_AV(avQ, 1, 0, 3) bvL[1][0] = LDB(1, 0, 3); MFMAQ(avP, bvL[0], 0) SB0
        /* L3 */ RD_AV(avP, 1, 2, 0) bvL[1][1] = LDB(1, 1, 3); MFMAQ(avQ, bvL[1], 0) SB0
        /* L4 */ RD_AV(avQ, 1, 2, 1) MFMAQ(avP, bvE[0], 2) ST32(0) SB0
        /* L5 */ RD_AV(avP, 1, 2, 2) MFMAQ(avQ, bvE[1], 2) ST32(1) SB0
        /* L6 */ RD_AV(avQ, 1, 2, 3) MFMAQ(avP, bvL[0], 2) SB0
        /* L7 */ MFMAQ(avQ, bvL[1], 2) ST32(2) ST32(3)
#undef ST32
    }
#undef STG
#undef LDA
#undef LDB
#undef SB0
#undef BAR
#undef RD_AV
#undef MFMAQ
#undef TILE
}

// ---- fallback: plain fp32 tiled GEMM (only if ws too small; exact) ----
__global__ __launch_bounds__(256) void sgemm_fb(const float* __restrict__ A,
                                                const float* __restrict__ B,
                                                float* __restrict__ C) {
    __shared__ float sA[64][17];
    __shared__ float sB[16][65];
    int tx = threadIdx.x, ty = threadIdx.y;
    int bM = blockIdx.y * 64, bN = blockIdx.x * 64;
    int t = ty * 16 + tx;
    float acc[4][4] = {};
    for (int k0 = 0; k0 < K_DIM; k0 += 16) {
        __syncthreads();
#pragma unroll
        for (int e = 0; e < 4; ++e) {
            int idx = t * 4 + e;
            int r = idx >> 4, c = idx & 15;
            sA[r][c] = A[(size_t)(bM + r) * K_DIM + k0 + c];
            int r2 = idx >> 6, c2 = idx & 63;
            sB[r2][c2] = B[(size_t)(k0 + r2) * N_DIM + bN + c2];
        }
        __syncthreads();
#pragma unroll
        for (int k = 0; k < 16; ++k) {
            float ar[4], br[4];
#pragma unroll
            for (int q = 0; q < 4; ++q) { ar[q] = sA[ty * 4 + q][k]; br[q] = sB[k][tx * 4 + q]; }
#pragma unroll
            for (int q = 0; q < 4; ++q)
#pragma unroll
                for (int w = 0; w < 4; ++w)
                    acc[q][w] += ar[q] * br[w];
        }
    }
#pragma unroll
    for (int q = 0; q < 4; ++q)
#pragma unroll
        for (int w = 0; w < 4; ++w)
            C[(size_t)(bM + ty * 4 + q) * N_DIM + bN + tx * 4 + w] = acc[q][w];
}

extern "C" void kernel_launch(void* const* d_in, const int* in_sizes, int n_in,
                              void* d_out, int out_size, void* d_ws, size_t ws_size,
                              hipStream_t stream) {
    const float* A = (const float*)d_in[0];
    const float* B = (const float*)d_in[1];
    float* C = (float*)d_out;

    size_t needA = (size_t)M_DIM * K_DIM * sizeof(unsigned short);
    size_t needB = (size_t)K_DIM * N_DIM * sizeof(unsigned short);

    if (ws_size >= needA + needB) {
        unsigned short* Aw = (unsigned short*)d_ws;
        unsigned short* Bw = Aw + (size_t)M_DIM * K_DIM;
        cvt_kernel<<<2048 + 1024, 256, 0, stream>>>(A, B, Aw, Bw);
        gemm8_kernel<<<(M_DIM / 256) * (N_DIM / 256), 512, 0, stream>>>(Aw, Bw, C);
    } else {
        sgemm_fb<<<dim3(N_DIM / 64, M_DIM / 64), dim3(16, 16), 0, stream>>>(A, B, C);
    }
}

// Round 14
// 51.427 us; speedup vs baseline: 1.0086x; 1.0086x over previous
//
#include <hip/hip_runtime.h>
#include <hip/hip_bf16.h>

#define M_DIM 4096
#define N_DIM 4096
#define K_DIM 1024
#define NT (K_DIM / 64)   // 16 K-tiles of BK=64

typedef short short8 __attribute__((ext_vector_type(8)));
typedef unsigned short ushort8 __attribute__((ext_vector_type(8)));
typedef unsigned short ushort4v __attribute__((ext_vector_type(4)));
typedef float f32x4 __attribute__((ext_vector_type(4)));
typedef float f32x16 __attribute__((ext_vector_type(16)));

// fp32 -> bf16 round-to-nearest-even (bias-free over the K-sum)
__device__ __forceinline__ unsigned short f2bf_rne(float f) {
    union { float f; unsigned u; } v;
    v.f = f;
    unsigned u = v.u;
    u += 0x7FFFu + ((u >> 16) & 1u);
    return (unsigned short)(u >> 16);
}

// async global->LDS, 16B/lane. LDS dest = wave-uniform base + lane*16.
__device__ __forceinline__ void gload16(const void* g, void* l) {
    __builtin_amdgcn_global_load_lds(
        (const __attribute__((address_space(1))) void*)g,
        (__attribute__((address_space(3))) void*)l,
        16, 0, 0);
}

// ---- merged conversion (R7-verified, at HBM roofline ~7.6us) ----
__global__ __launch_bounds__(256) void cvt_kernel(const float* __restrict__ A,
                                                  const float* __restrict__ B,
                                                  unsigned short* __restrict__ Aw,
                                                  unsigned short* __restrict__ Bw) {
    __shared__ unsigned short tile[64][68];   // +4 pad
    if (blockIdx.x < 2048) {
        size_t i = (size_t)blockIdx.x * 256 + threadIdx.x;
        const f32x4* s = (const f32x4*)A + i * 2;
        f32x4 v0 = s[0], v1 = s[1];
        ushort8 o;
        o[0] = f2bf_rne(v0[0]); o[1] = f2bf_rne(v0[1]);
        o[2] = f2bf_rne(v0[2]); o[3] = f2bf_rne(v0[3]);
        o[4] = f2bf_rne(v1[0]); o[5] = f2bf_rne(v1[1]);
        o[6] = f2bf_rne(v1[2]); o[7] = f2bf_rne(v1[3]);
        *(ushort8*)(Aw + i * 8) = o;
    } else {
        int bb = blockIdx.x - 2048;               // 0..1023
        int bn = bb & 63, bk = bb >> 6;           // 64 n-tiles x 16 k-tiles
        int n0 = bn * 64, k0 = bk * 64;
        int kr = threadIdx.x >> 4;                // 0..15
        int nc = threadIdx.x & 15;
#pragma unroll
        for (int p = 0; p < 4; ++p) {
            int k = kr + p * 16;
            f32x4 v = *(const f32x4*)&B[(size_t)(k0 + k) * N_DIM + n0 + nc * 4];
            ushort4v u;
            u[0] = f2bf_rne(v[0]); u[1] = f2bf_rne(v[1]);
            u[2] = f2bf_rne(v[2]); u[3] = f2bf_rne(v[3]);
            *(ushort4v*)&tile[k][nc * 4] = u;
        }
        __syncthreads();
#pragma unroll
        for (int p = 0; p < 4; ++p) {
            int n = kr + p * 16;
            ushort4v o;
#pragma unroll
            for (int j = 0; j < 4; ++j) o[j] = tile[nc * 4 + j][n];
            *(ushort4v*)&Bw[(size_t)(n0 + n) * K_DIM + k0 + nc * 4] = o;
        }
    }
}

// ---- 256x256x64 GEMM, R7 schedule on mfma_f32_32x32x16_bf16 ----
// vs R13: widened LDS swizzle slot = chunk ^ (row&7) ^ ((row>>3)&3) to kill the
// 3.15M 4-way bank conflicts (32x32's k-chunk varies only per lane-half).
__global__ __launch_bounds__(512, 1) void gemm8_kernel(const unsigned short* __restrict__ A,
                                                       const unsigned short* __restrict__ Bt,
                                                       float* __restrict__ C) {
    __shared__ __align__(16) unsigned short lds[2][2][256 * 64];  // [buf][0=A,1=B]

    int bid = blockIdx.x;
    int xcd = bid & 7, ii = bid >> 3;
    int tm = xcd * 2 + (ii & 1);
    int tn = ii >> 1;
    int bM = tm * 256, bN = tn * 256;

    int tid = threadIdx.x;
    int wid = tid >> 6, lane = tid & 63;
    int wm = wid >> 2, wn = wid & 3;

    int srow = lane >> 3;
    int cslot = (lane & 7) ^ srow ^ (wid & 3);   // inverse swizzle incl. (row>>3)&3
    int stg_row = wid * 8 + srow;

    const unsigned short* gA = A + (size_t)(bM + stg_row) * K_DIM + cslot * 8;
    const unsigned short* gB = Bt + (size_t)(bN + stg_row) * K_DIM + cslot * 8;

#define STG(mat, unit, buf, kt)                                                        \
    gload16((mat ? gB : gA) + (size_t)((unit) * 64) * K_DIM + (size_t)(kt) * 64,       \
            (char*)&lds[(buf)][(mat)][0] + (unit) * 8192 + wid * 1024)

    // 32x32 fragment addressing: row = base + m*32 + (lane&31); 16B slot for
    // k-step s = (s*2 + (lane>>5)) ^ (row&7) ^ ((row>>3)&3)
    int rA = wm * 128 + (lane & 31);
    int rB = wn * 64 + (lane & 31);
    int l5 = lane >> 5;
    int swz = (lane & 7) ^ ((lane >> 3) & 3);    // row&7 ^ (row>>3)&3 for these rows

#define LDA(buf, m, s) \
    (*(const short8*)&lds[(buf)][0][(rA + (m) * 32) * 64 + ((((s) * 2 + l5) ^ swz) * 8)])
#define LDB(buf, n, s) \
    (*(const short8*)&lds[(buf)][1][(rB + (n) * 32) * 64 + ((((s) * 2 + l5) ^ swz) * 8)])

    f32x16 acc[4][2];
#pragma unroll
    for (int m = 0; m < 4; ++m)
#pragma unroll
        for (int n = 0; n < 2; ++n)
            acc[m][n] = (f32x16)(0.f);

    short8 avP[2], avQ[2];       // m-pair ping-pong (one k-step)
    short8 bvE[2][2], bvL[2][2]; // [k-step 0|1][n] and [k-step 2|3][n]

#define SB0 __builtin_amdgcn_sched_barrier(0);
#define BAR                                    \
    __builtin_amdgcn_sched_barrier(0);         \
    __builtin_amdgcn_s_barrier();              \
    __builtin_amdgcn_sched_barrier(0);

#define RD_AV(AV, BUF, MB, SS)                 \
    AV[0] = LDA(BUF, (MB), SS);                \
    AV[1] = LDA(BUF, (MB) + 1, SS);

#define MFMAQ(AV, BVS, MB)                                                             \
    __builtin_amdgcn_s_setprio(1);                                                     \
    _Pragma("unroll") for (int m2 = 0; m2 < 2; ++m2)                                   \
        _Pragma("unroll") for (int n = 0; n < 2; ++n)                                  \
            acc[(MB) + m2][n] = __builtin_amdgcn_mfma_f32_32x32x16_bf16(               \
                AV[m2], BVS[n], acc[(MB) + m2][n], 0, 0, 0);                           \
    __builtin_amdgcn_s_setprio(0);

    // steady tile: HT2 = (t+2 < NT) compile-path, VME = boundary vmcnt string
#define TILE(t, CB, NB, HT2, VME)                                                      \
    {                                                                                  \
        /* q0: MFMA m01@s0 */                                                          \
        RD_AV(avQ, CB, 2, 0) bvL[0][0] = LDB(CB, 0, 2);                                \
        STG(0, 1, NB, (t) + 1);                                                        \
        MFMAQ(avP, bvE[0], 0) SB0                                                      \
        /* q1: MFMA m23@s0 */                                                          \
        RD_AV(avP, CB, 0, 1) bvL[0][1] = LDB(CB, 1, 2);                                \
        STG(0, 3, NB, (t) + 1);                                                        \
        MFMAQ(avQ, bvE[0], 2) SB0                                                      \
        /* q2: MFMA m01@s1 */                                                          \
        RD_AV(avQ, CB, 2, 1) bvL[1][0] = LDB(CB, 0, 3);                                \
        MFMAQ(avP, bvE[1], 0) SB0                                                      \
        /* q3: MFMA m23@s1 */                                                          \
        RD_AV(avP, CB, 0, 2) bvL[1][1] = LDB(CB, 1, 3);                                \
        MFMAQ(avQ, bvE[1], 2)                                                          \
        asm volatile("s_waitcnt vmcnt(2)" ::: "memory");                               \
        BAR                                                                            \
        /* q4: MFMA m01@s2 */                                                          \
        RD_AV(avQ, CB, 2, 2) bvE[0][0] = LDB(NB, 0, 0);                                \
        if (HT2) { STG(1, 0, CB, (t) + 2); }                                           \
        MFMAQ(avP, bvL[0], 0)                                                          \
        BAR                                                                            \
        /* q5: MFMA m23@s2 */                                                          \
        RD_AV(avP, CB, 0, 3) bvE[0][1] = LDB(NB, 1, 0);                                \
        if (HT2) { STG(1, 1, CB, (t) + 2); STG(0, 0, CB, (t) + 2); }                   \
        MFMAQ(avQ, bvL[0], 2) SB0                                                      \
        /* q6: MFMA m01@s3 */                                                          \
        RD_AV(avQ, CB, 2, 3) bvE[1][0] = LDB(NB, 0, 1);                                \
        if (HT2) { STG(1, 2, CB, (t) + 2); STG(0, 2, CB, (t) + 2); }                   \
        MFMAQ(avP, bvL[1], 0) SB0                                                      \
        /* q7: MFMA m23@s3 */                                                          \
        RD_AV(avP, NB, 0, 0) bvE[1][1] = LDB(NB, 1, 1);                                \
        if (HT2) { STG(1, 3, CB, (t) + 2); }                                           \
        MFMAQ(avQ, bvL[1], 2)                                                          \
        asm volatile("s_waitcnt " VME ::: "memory");                                   \
        BAR                                                                            \
    }

    // ---- prologue: t0 all 8 units + t1's 6 (steady q4-7 order) ----
    STG(1, 0, 0, 0); STG(1, 1, 0, 0); STG(1, 2, 0, 0); STG(1, 3, 0, 0);
    STG(0, 0, 0, 0); STG(0, 1, 0, 0); STG(0, 2, 0, 0); STG(0, 3, 0, 0);
    STG(1, 0, 1, 1); STG(1, 1, 1, 1); STG(0, 0, 1, 1);
    STG(1, 2, 1, 1); STG(0, 2, 1, 1); STG(1, 3, 1, 1);
    asm volatile("s_waitcnt vmcnt(6)" ::: "memory");
    BAR
    // pre-reads for tile0 q0
    bvE[0][0] = LDB(0, 0, 0); bvE[0][1] = LDB(0, 1, 0);
    bvE[1][0] = LDB(0, 0, 1); bvE[1][1] = LDB(0, 1, 1);
    RD_AV(avP, 0, 0, 0)
    SB0

    for (int t = 0; t < NT - 2; t += 2) {
        TILE(t, 0, 1, true, "vmcnt(6)")
        TILE(t + 1, 1, 0, true, "vmcnt(6)")
    }
    TILE(NT - 2, 0, 1, false, "vmcnt(0)")

    // ---- last tile (buf 1): m-major order, barrier-free, fused C stores ----
    // C/D layout (m74/m101): col = lane&31, row = (r&3) + 8*(r>>2) + 4*(lane>>5)
    {
        size_t crow = (size_t)bM + wm * 128 + l5 * 4;
        int ccol = bN + wn * 64 + (lane & 31);
#define ST32(M)                                                                        \
        _Pragma("unroll") for (int n = 0; n < 2; ++n)                                  \
            _Pragma("unroll") for (int r = 0; r < 16; ++r)                             \
                C[(crow + (M) * 32 + (r & 3) + 8 * (r >> 2)) * N_DIM +                 \
                  ccol + n * 32] = acc[(M)][n][r];
        /* L0 */ RD_AV(avQ, 1, 0, 1) bvL[0][0] = LDB(1, 0, 2); MFMAQ(avP, bvE[0], 0) SB0
        /* L1 */ RD_AV(avP, 1, 0, 2) bvL[0][1] = LDB(1, 1, 2); MFMAQ(avQ, bvE[1], 0) SB0
        /* L2 */ RD_AV(avQ, 1, 0, 3) bvL[1][0] = LDB(1, 0, 3); MFMAQ(avP, bvL[0], 0) SB0
        /* L3 */ RD_AV(avP, 1, 2, 0) bvL[1][1] = LDB(1, 1, 3); MFMAQ(avQ, bvL[1], 0) SB0
        /* L4 */ RD_AV(avQ, 1, 2, 1) MFMAQ(avP, bvE[0], 2) ST32(0) SB0
        /* L5 */ RD_AV(avP, 1, 2, 2) MFMAQ(avQ, bvE[1], 2) ST32(1) SB0
        /* L6 */ RD_AV(avQ, 1, 2, 3) MFMAQ(avP, bvL[0], 2) SB0
        /* L7 */ MFMAQ(avQ, bvL[1], 2) ST32(2) ST32(3)
#undef ST32
    }
#undef STG
#undef LDA
#undef LDB
#undef SB0
#undef BAR
#undef RD_AV
#undef MFMAQ
#undef TILE
}

// ---- fallback: plain fp32 tiled GEMM (only if ws too small; exact) ----
__global__ __launch_bounds__(256) void sgemm_fb(const float* __restrict__ A,
                                                const float* __restrict__ B,
                                                float* __restrict__ C) {
    __shared__ float sA[64][17];
    __shared__ float sB[16][65];
    int tx = threadIdx.x, ty = threadIdx.y;
    int bM = blockIdx.y * 64, bN = blockIdx.x * 64;
    int t = ty * 16 + tx;
    float acc[4][4] = {};
    for (int k0 = 0; k0 < K_DIM; k0 += 16) {
        __syncthreads();
#pragma unroll
        for (int e = 0; e < 4; ++e) {
            int idx = t * 4 + e;
            int r = idx >> 4, c = idx & 15;
            sA[r][c] = A[(size_t)(bM + r) * K_DIM + k0 + c];
            int r2 = idx >> 6, c2 = idx & 63;
            sB[r2][c2] = B[(size_t)(k0 + r2) * N_DIM + bN + c2];
        }
        __syncthreads();
#pragma unroll
        for (int k = 0; k < 16; ++k) {
            float ar[4], br[4];
#pragma unroll
            for (int q = 0; q < 4; ++q) { ar[q] = sA[ty * 4 + q][k]; br[q] = sB[k][tx * 4 + q]; }
#pragma unroll
            for (int q = 0; q < 4; ++q)
#pragma unroll
                for (int w = 0; w < 4; ++w)
                    acc[q][w] += ar[q] * br[w];
        }
    }
#pragma unroll
    for (int q = 0; q < 4; ++q)
#pragma unroll
        for (int w = 0; w < 4; ++w)
            C[(size_t)(bM + ty * 4 + q) * N_DIM + bN + tx * 4 + w] = acc[q][w];
}

extern "C" void kernel_launch(void* const* d_in, const int* in_sizes, int n_in,
                              void* d_out, int out_size, void* d_ws, size_t ws_size,
                              hipStream_t stream) {
    const float* A = (const float*)d_in[0];
    const float* B = (const float*)d_in[1];
    float* C = (float*)d_out;

    size_t needA = (size_t)M_DIM * K_DIM * sizeof(unsigned short);
    size_t needB = (size_t)K_DIM * N_DIM * sizeof(unsigned short);

    if (ws_size >= needA + needB) {
        unsigned short* Aw = (unsigned short*)d_ws;
        unsigned short* Bw = Aw + (size_t)M_DIM * K_DIM;
        cvt_kernel<<<2048 + 1024, 256, 0, stream>>>(A, B, Aw, Bw);
        gemm8_kernel<<<(M_DIM / 256) * (N_DIM / 256), 512, 0, stream>>>(Aw, Bw, C);
    } else {
        sgemm_fb<<<dim3(N_DIM / 64, M_DIM / 64), dim3(16, 16), 0, stream>>>(A, B, C);
    }
}

// Round 15
// 48.814 us; speedup vs baseline: 1.0626x; 1.0535x over previous
//
#include <hip/hip_runtime.h>
#include <hip/hip_bf16.h>

#define M_DIM 4096
#define N_DIM 4096
#define K_DIM 1024
#define NT (K_DIM / 64)   // 16 K-tiles of BK=64

typedef short short8 __attribute__((ext_vector_type(8)));
typedef unsigned short ushort8 __attribute__((ext_vector_type(8)));
typedef unsigned short ushort4v __attribute__((ext_vector_type(4)));
typedef float f32x4 __attribute__((ext_vector_type(4)));

// fp32 -> bf16 round-to-nearest-even (bias-free over the K-sum)
__device__ __forceinline__ unsigned short f2bf_rne(float f) {
    union { float f; unsigned u; } v;
    v.f = f;
    unsigned u = v.u;
    u += 0x7FFFu + ((u >> 16) & 1u);
    return (unsigned short)(u >> 16);
}

// async global->LDS, 16B/lane. LDS dest = wave-uniform base + lane*16.
__device__ __forceinline__ void gload16(const void* g, void* l) {
    __builtin_amdgcn_global_load_lds(
        (const __attribute__((address_space(1))) void*)g,
        (__attribute__((address_space(3))) void*)l,
        16, 0, 0);
}

// ---- merged conversion ----
// blocks 0..2047:    A fp32 -> bf16 (same M x K layout), 8 elems/thread
// blocks 2048..3071: B fp32 (K x N) -> Bt bf16 (N x K), 64x64 tile, vectorized
__global__ __launch_bounds__(256) void cvt_kernel(const float* __restrict__ A,
                                                  const float* __restrict__ B,
                                                  unsigned short* __restrict__ Aw,
                                                  unsigned short* __restrict__ Bw) {
    __shared__ unsigned short tile[64][68];   // +4 pad
    if (blockIdx.x < 2048) {
        size_t i = (size_t)blockIdx.x * 256 + threadIdx.x;
        const f32x4* s = (const f32x4*)A + i * 2;
        f32x4 v0 = s[0], v1 = s[1];
        ushort8 o;
        o[0] = f2bf_rne(v0[0]); o[1] = f2bf_rne(v0[1]);
        o[2] = f2bf_rne(v0[2]); o[3] = f2bf_rne(v0[3]);
        o[4] = f2bf_rne(v1[0]); o[5] = f2bf_rne(v1[1]);
        o[6] = f2bf_rne(v1[2]); o[7] = f2bf_rne(v1[3]);
        *(ushort8*)(Aw + i * 8) = o;
    } else {
        int bb = blockIdx.x - 2048;               // 0..1023
        int bn = bb & 63, bk = bb >> 6;           // 64 n-tiles x 16 k-tiles
        int n0 = bn * 64, k0 = bk * 64;
        int kr = threadIdx.x >> 4;                // 0..15
        int nc = threadIdx.x & 15;
#pragma unroll
        for (int p = 0; p < 4; ++p) {
            int k = kr + p * 16;
            f32x4 v = *(const f32x4*)&B[(size_t)(k0 + k) * N_DIM + n0 + nc * 4];
            ushort4v u;
            u[0] = f2bf_rne(v[0]); u[1] = f2bf_rne(v[1]);
            u[2] = f2bf_rne(v[2]); u[3] = f2bf_rne(v[3]);
            *(ushort4v*)&tile[k][nc * 4] = u;
        }
        __syncthreads();
#pragma unroll
        for (int p = 0; p < 4; ++p) {
            int n = kr + p * 16;
            ushort4v o;
#pragma unroll
            for (int j = 0; j < 4; ++j) o[j] = tile[nc * 4 + j][n];
            *(ushort4v*)&Bw[(size_t)(n0 + n) * K_DIM + k0 + nc * 4] = o;
        }
    }
}

// ---- 256x256x64 GEMM, balanced 8-subphase schedule (session-best, 48.89us) ----
// 8 waves (2Mx4N), per-wave 128x64 = acc[8][4]. LDS 128 KiB dbuf, XOR swizzle.
// Subphase q: MFMA 8 (m-pair x 4n x 1k) using regs read in q-1; issue 3 ds_reads
// for q+1 (A m-pair + 1 B frag); STG budget 8 gloads/tile. Sync: 3 barriers
// (end-q3 +vmcnt(2), end-q4, end-q7 +vmcnt(6)) per tile.
__global__ __launch_bounds__(512, 2) void gemm8_kernel(const unsigned short* __restrict__ A,
                                                       const unsigned short* __restrict__ Bt,
                                                       float* __restrict__ C) {
    __shared__ __align__(16) unsigned short lds[2][2][256 * 64];  // [buf][0=A,1=B]

    int bid = blockIdx.x;
    int xcd = bid & 7, ii = bid >> 3;
    int tm = xcd * 2 + (ii & 1);
    int tn = ii >> 1;
    int bM = tm * 256, bN = tn * 256;

    int tid = threadIdx.x;
    int wid = tid >> 6, lane = tid & 63;
    int wm = wid >> 2, wn = wid & 3;

    int srow = lane >> 3;
    int cslot = (lane & 7) ^ srow;
    int stg_row = wid * 8 + srow;

    const unsigned short* gA = A + (size_t)(bM + stg_row) * K_DIM + cslot * 8;
    const unsigned short* gB = Bt + (size_t)(bN + stg_row) * K_DIM + cslot * 8;

#define STG(mat, unit, buf, kt)                                                        \
    gload16((mat ? gB : gA) + (size_t)((unit) * 64) * K_DIM + (size_t)(kt) * 64,       \
            (char*)&lds[(buf)][(mat)][0] + (unit) * 8192 + wid * 1024)

    int rA = wm * 128 + (lane & 15);
    int rB = wn * 64 + (lane & 15);
    int rslot = lane >> 4;
    int l7 = lane & 7;

#define LDA(buf, m, k) \
    (*(const short8*)&lds[(buf)][0][(rA + (m) * 16) * 64 + ((((k) * 4 + rslot) ^ l7) * 8)])
#define LDB(buf, n, k) \
    (*(const short8*)&lds[(buf)][1][(rB + (n) * 16) * 64 + ((((k) * 4 + rslot) ^ l7) * 8)])

    f32x4 acc[8][4];
#pragma unroll
    for (int m = 0; m < 8; ++m)
#pragma unroll
        for (int n = 0; n < 4; ++n)
            acc[m][n] = (f32x4){0.f, 0.f, 0.f, 0.f};

    short8 avP[2], avQ[2];     // m-pair ping-pong
    short8 bv0[4], bv1[4];     // k0 / k1 B fragments

#define SB0 __builtin_amdgcn_sched_barrier(0);
#define BAR                                    \
    __builtin_amdgcn_sched_barrier(0);         \
    __builtin_amdgcn_s_barrier();              \
    __builtin_amdgcn_sched_barrier(0);

#define RD_AV(AV, BUF, MB, KK)                 \
    AV[0] = LDA(BUF, (MB), KK);                \
    AV[1] = LDA(BUF, (MB) + 1, KK);

#define MFMAQ(AV, BV, MB)                                                              \
    __builtin_amdgcn_s_setprio(1);                                                     \
    _Pragma("unroll") for (int m2 = 0; m2 < 2; ++m2)                                   \
        _Pragma("unroll") for (int n = 0; n < 4; ++n)                                  \
            acc[(MB) + m2][n] = __builtin_amdgcn_mfma_f32_16x16x32_bf16(               \
                AV[m2], BV[n], acc[(MB) + m2][n], 0, 0, 0);                            \
    __builtin_amdgcn_s_setprio(0);

    // steady tile: HT2 = (t+2 < NT) compile-path, VME = boundary vmcnt string
#define TILE(t, CB, NB, HT2, VME)                                                      \
    {                                                                                  \
        /* q0 */                                                                       \
        RD_AV(avQ, CB, 2, 0) bv1[0] = LDB(CB, 0, 1);                                   \
        STG(0, 1, NB, (t) + 1);                                                        \
        MFMAQ(avP, bv0, 0) SB0                                                         \
        /* q1 */                                                                       \
        RD_AV(avP, CB, 4, 0) bv1[1] = LDB(CB, 1, 1);                                   \
        STG(0, 3, NB, (t) + 1);                                                        \
        MFMAQ(avQ, bv0, 2) SB0                                                         \
        /* q2 */                                                                       \
        RD_AV(avQ, CB, 6, 0) bv1[2] = LDB(CB, 2, 1);                                   \
        MFMAQ(avP, bv0, 4) SB0                                                         \
        /* q3 */                                                                       \
        RD_AV(avP, CB, 0, 1) bv1[3] = LDB(CB, 3, 1);                                   \
        MFMAQ(avQ, bv0, 6)                                                             \
        asm volatile("s_waitcnt vmcnt(2)" ::: "memory");                               \
        BAR                                                                            \
        /* q4 */                                                                       \
        RD_AV(avQ, CB, 2, 1) bv0[0] = LDB(NB, 0, 0);                                   \
        if (HT2) { STG(1, 0, CB, (t) + 2); }                                           \
        MFMAQ(avP, bv1, 0)                                                             \
        BAR                                                                            \
        /* q5 */                                                                       \
        RD_AV(avP, CB, 4, 1) bv0[1] = LDB(NB, 1, 0);                                   \
        if (HT2) { STG(1, 1, CB, (t) + 2); STG(0, 0, CB, (t) + 2); }                   \
        MFMAQ(avQ, bv1, 2) SB0                                                         \
        /* q6 */                                                                       \
        RD_AV(avQ, CB, 6, 1) bv0[2] = LDB(NB, 2, 0);                                   \
        if (HT2) { STG(1, 2, CB, (t) + 2); STG(0, 2, CB, (t) + 2); }                   \
        MFMAQ(avP, bv1, 4) SB0                                                         \
        /* q7 */                                                                       \
        RD_AV(avP, NB, 0, 0) bv0[3] = LDB(NB, 3, 0);                                   \
        if (HT2) { STG(1, 3, CB, (t) + 2); }                                           \
        MFMAQ(avQ, bv1, 6)                                                             \
        asm volatile("s_waitcnt " VME ::: "memory");                                   \
        BAR                                                                            \
    }

    // ---- prologue: t0 all 8 units + t1's 6 (steady q4-7 order) ----
    STG(1, 0, 0, 0); STG(1, 1, 0, 0); STG(1, 2, 0, 0); STG(1, 3, 0, 0);
    STG(0, 0, 0, 0); STG(0, 1, 0, 0); STG(0, 2, 0, 0); STG(0, 3, 0, 0);
    STG(1, 0, 1, 1); STG(1, 1, 1, 1); STG(0, 0, 1, 1);
    STG(1, 2, 1, 1); STG(0, 2, 1, 1); STG(1, 3, 1, 1);
    asm volatile("s_waitcnt vmcnt(6)" ::: "memory");
    BAR
    // pre-reads for tile0 q0
    bv0[0] = LDB(0, 0, 0); bv0[1] = LDB(0, 1, 0);
    bv0[2] = LDB(0, 2, 0); bv0[3] = LDB(0, 3, 0);
    RD_AV(avP, 0, 0, 0)
    SB0

    for (int t = 0; t < NT - 2; t += 2) {
        TILE(t, 0, 1, true, "vmcnt(6)")
        TILE(t + 1, 1, 0, true, "vmcnt(6)")
    }
    TILE(NT - 2, 0, 1, false, "vmcnt(0)")

    // ---- last tile (buf 1): barrier-free, fused C stores ----
    {
        size_t crow = (size_t)bM + wm * 128 + ((lane >> 4) << 2);
        int ccol = bN + wn * 64 + (lane & 15);
#define ST2(MB)                                                                        \
        _Pragma("unroll") for (int m2 = 0; m2 < 2; ++m2)                               \
            _Pragma("unroll") for (int n = 0; n < 4; ++n)                              \
                _Pragma("unroll") for (int r = 0; r < 4; ++r)                          \
                    C[(crow + ((MB) + m2) * 16 + r) * N_DIM + ccol + n * 16] =         \
                        acc[(MB) + m2][n][r];
        /* q0 */ RD_AV(avQ, 1, 2, 0) bv1[0] = LDB(1, 0, 1); MFMAQ(avP, bv0, 0) SB0
        /* q1 */ RD_AV(avP, 1, 4, 0) bv1[1] = LDB(1, 1, 1); MFMAQ(avQ, bv0, 2) SB0
        /* q2 */ RD_AV(avQ, 1, 6, 0) bv1[2] = LDB(1, 2, 1); MFMAQ(avP, bv0, 4) SB0
        /* q3 */ RD_AV(avP, 1, 0, 1) bv1[3] = LDB(1, 3, 1); MFMAQ(avQ, bv0, 6) SB0
        /* q4 */ RD_AV(avQ, 1, 2, 1) MFMAQ(avP, bv1, 0) ST2(0) SB0
        /* q5 */ RD_AV(avP, 1, 4, 1) MFMAQ(avQ, bv1, 2) ST2(2) SB0
        /* q6 */ RD_AV(avQ, 1, 6, 1) MFMAQ(avP, bv1, 4) ST2(4) SB0
        /* q7 */ MFMAQ(avQ, bv1, 6) ST2(6)
#undef ST2
    }
#undef STG
#undef LDA
#undef LDB
#undef SB0
#undef BAR
#undef RD_AV
#undef MFMAQ
#undef TILE
}

// ---- fallback: plain fp32 tiled GEMM (only if ws too small; exact) ----
__global__ __launch_bounds__(256) void sgemm_fb(const float* __restrict__ A,
                                                const float* __restrict__ B,
                                                float* __restrict__ C) {
    __shared__ float sA[64][17];
    __shared__ float sB[16][65];
    int tx = threadIdx.x, ty = threadIdx.y;
    int bM = blockIdx.y * 64, bN = blockIdx.x * 64;
    int t = ty * 16 + tx;
    float acc[4][4] = {};
    for (int k0 = 0; k0 < K_DIM; k0 += 16) {
        __syncthreads();
#pragma unroll
        for (int e = 0; e < 4; ++e) {
            int idx = t * 4 + e;
            int r = idx >> 4, c = idx & 15;
            sA[r][c] = A[(size_t)(bM + r) * K_DIM + k0 + c];
            int r2 = idx >> 6, c2 = idx & 63;
            sB[r2][c2] = B[(size_t)(k0 + r2) * N_DIM + bN + c2];
        }
        __syncthreads();
#pragma unroll
        for (int k = 0; k < 16; ++k) {
            float ar[4], br[4];
#pragma unroll
            for (int q = 0; q < 4; ++q) { ar[q] = sA[ty * 4 + q][k]; br[q] = sB[k][tx * 4 + q]; }
#pragma unroll
            for (int q = 0; q < 4; ++q)
#pragma unroll
                for (int w = 0; w < 4; ++w)
                    acc[q][w] += ar[q] * br[w];
        }
    }
#pragma unroll
    for (int q = 0; q < 4; ++q)
#pragma unroll
        for (int w = 0; w < 4; ++w)
            C[(size_t)(bM + ty * 4 + q) * N_DIM + bN + tx * 4 + w] = acc[q][w];
}

extern "C" void kernel_launch(void* const* d_in, const int* in_sizes, int n_in,
                              void* d_out, int out_size, void* d_ws, size_t ws_size,
                              hipStream_t stream) {
    const float* A = (const float*)d_in[0];
    const float* B = (const float*)d_in[1];
    float* C = (float*)d_out;

    size_t needA = (size_t)M_DIM * K_DIM * sizeof(unsigned short);
    size_t needB = (size_t)K_DIM * N_DIM * sizeof(unsigned short);

    if (ws_size >= needA + needB) {
        unsigned short* Aw = (unsigned short*)d_ws;
        unsigned short* Bw = Aw + (size_t)M_DIM * K_DIM;
        cvt_kernel<<<2048 + 1024, 256, 0, stream>>>(A, B, Aw, Bw);
        gemm8_kernel<<<(M_DIM / 256) * (N_DIM / 256), 512, 0, stream>>>(Aw, Bw, C);
    } else {
        sgemm_fb<<<dim3(N_DIM / 64, M_DIM / 64), dim3(16, 16), 0, stream>>>(A, B, C);
    }
}